// Round 13
// baseline (678.884 us; speedup 1.0000x reference)
//
#include <hip/hip_runtime.h>

// ---------------- problem constants ----------------
#define B_    16
#define M_    128
#define N_    128
#define DIN   12
#define D_    64
#define H_    128
#define MODES 16
#define NL    4
#define NPIX  262144       // B*M*N

typedef float  f32x2 __attribute__((ext_vector_type(2)));
typedef float  f32x4 __attribute__((ext_vector_type(4)));
typedef short  s16x8 __attribute__((ext_vector_type(8)));
typedef unsigned int u32x2 __attribute__((ext_vector_type(2)));
typedef unsigned int u32x4 __attribute__((ext_vector_type(4)));
typedef __fp16 h16x2 __attribute__((ext_vector_type(2)));   // matches cvt_pkrtz / fdot2

// ---------------- workspace layout (BYTE offsets) ----------------
#define WSB_X      0L           // bf16 X [B][M][N][64]           33554432
#define WSB_XSX    33554432L    // bf16 XSx [b][m][nc][o]         33554432
#define WSB_BF     67108864L    // fwd basis bf16 [kp=32][n=128]  8192
#define WSB_BI     67117056L    // inv basis bf16 [n=128][kp=32]  8192
#define WSB_U      67125248L    // u[4][128] f32                  2048
#define WSB_D      67127296L    // d[4] f32 (+pad)                16
#define WSB_WFF    67127312L    // FF weights bf16 (3x4x8192 u16) 196608
#define WSB_WMIX   67323920L    // mix weights u32 = f16(re,im) [ax][l][k][i][o] 2097152
#define WS_NEEDED  69421072L

__device__ __forceinline__ unsigned short f2bf(float f){
    unsigned int u = __float_as_uint(f);
    u += 0x7fffu + ((u >> 16) & 1u);
    return (unsigned short)(u >> 16);
}
__device__ __forceinline__ float bf2f(unsigned short s){
    return __uint_as_float(((unsigned int)s) << 16);
}
__device__ __forceinline__ unsigned int cvtpk(float lo, float hi){   // f32x2 -> bf16x2
    unsigned int r;
    asm("v_cvt_pk_bf16_f32 %0, %1, %2" : "=v"(r) : "v"(lo), "v"(hi));
    return r;
}
__device__ __forceinline__ unsigned int pkh(float lo, float hi){     // f32x2 -> f16x2
    h16x2 h = __builtin_amdgcn_cvt_pkrtz(lo, hi);
    return __builtin_bit_cast(unsigned int, h);
}
__device__ __forceinline__ float fdot2u(unsigned int a, unsigned int b, float c){
    h16x2 ha = __builtin_bit_cast(h16x2, a);
    h16x2 hb = __builtin_bit_cast(h16x2, b);
    return __builtin_amdgcn_fdot2(ha, hb, c, false);
}

// ============ init: bf16 basis tables + collapsed output head ============
__global__ void k_init(const float* __restrict__ out_w1, const float* __restrict__ out_b1,
                       const float* __restrict__ out_w2, const float* __restrict__ out_b2,
                       const float* __restrict__ fc_w2, const float* __restrict__ fc_b2,
                       float* __restrict__ ws){
    __shared__ float v_s[64];
    __shared__ float c_s;
    int t = threadIdx.x;
    if (t < 64){
        float a = 0.f;
        for (int j = 0; j < H_; j++) a += out_w1[t*H_ + j] * out_w2[j];
        v_s[t] = a;
    }
    if (t == 64){
        float a = 0.f;
        for (int j = 0; j < H_; j++) a += out_b1[j] * out_w2[j];
        c_s = a + out_b2[0];
    }
    __syncthreads();
    float* uw = (float*)((char*)ws + WSB_U);
    float* dw = (float*)((char*)ws + WSB_D);
    if (t < 128){
        for (int l = 0; l < NL; l++){
            float a = 0.f;
            for (int o = 0; o < D_; o++) a += fc_w2[(l*H_ + t)*D_ + o] * v_s[o];
            uw[l*128 + t] = a;
        }
    }
    if (t >= 128 && t < 132){
        int l = t - 128;
        float a = 0.f;
        for (int o = 0; o < D_; o++) a += fc_b2[l*D_ + o] * v_s[o];
        dw[l] = a + c_s;
    }
    const float isn = 0.08838834764831845f;  // 1/sqrt(128)
    unsigned short* bft = (unsigned short*)((char*)ws + WSB_BF);
    unsigned short* bit = (unsigned short*)((char*)ws + WSB_BI);
    for (int e = t; e < 4096; e += 256){
        { int kp = e >> 7, n = e & 127, k = kp >> 1;
          float ang = 6.283185307179586f * (float)((k*n) & 127) / 128.0f;
          bft[e] = f2bf((kp & 1) ? (-sinf(ang)*isn) : (cosf(ang)*isn)); }
        { int n = e >> 5, kp = e & 31, k = kp >> 1;
          float ang = 6.283185307179586f * (float)((k*n) & 127) / 128.0f;
          float val;
          if (kp & 1) val = (k == 0) ? 0.f : (-2.f*sinf(ang)*isn);
          else        val = ((k == 0) ? 1.f : 2.f) * cosf(ang) * isn;
          bit[e] = f2bf(val); }
    }
}

// ============ FF weights -> bf16 transposed ============
__global__ void k_wconv(const float* __restrict__ bc_w1, const float* __restrict__ fc_w1,
                        const float* __restrict__ bc_w2, float* __restrict__ ws){
    unsigned short* wb = (unsigned short*)((char*)ws + WSB_WFF);
    int e = blockIdx.x*256 + threadIdx.x;      // < 98304
    int a = e >> 15;
    int r = e & 32767;
    int l = r >> 13;
    int q = r & 8191;
    if (a == 0){
        int j = q >> 6, i = q & 63;
        wb[e] = f2bf(bc_w1[(l*D_ + i)*H_ + j]);
    } else if (a == 1){
        int j = q >> 6, i = q & 63;
        wb[e] = f2bf(fc_w1[(l*D_ + i)*H_ + j]);
    } else {
        int o = q >> 7, j = q & 127;
        wb[e] = f2bf(bc_w2[(l*H_ + j)*D_ + o]);
    }
}

// ============ mix weights -> packed f16 u32 (re,im) [ax][l][k][i][o] ============
__global__ void k_wmix(const float* __restrict__ fwy_re, const float* __restrict__ fwy_im,
                       const float* __restrict__ fwx_re, const float* __restrict__ fwx_im,
                       float* __restrict__ ws){
    unsigned int* wm = (unsigned int*)((char*)ws + WSB_WMIX);
    int e = blockIdx.x*256 + threadIdx.x;   // < 524288
    int ax = e >> 18;
    int r  = e & 262143;
    int l  = r >> 16;
    int k  = (r >> 12) & 15;
    int i  = (r >> 6) & 63;
    int o  = r & 63;
    long sidx = (((long)l*64 + i)*64 + o)*16 + k;
    float re = ax ? fwx_re[sidx] : fwy_re[sidx];
    float im = ax ? fwx_im[sidx] : fwy_im[sidx];
    wm[e] = pkh(re, im);
}

// ============ input embedding -> bf16 X ============
__global__ __launch_bounds__(256) void k_embed(const float* __restrict__ xin,
                                               const float* __restrict__ in_w,
                                               const float* __restrict__ in_b,
                                               unsigned short* __restrict__ X){
    long row = (long)blockIdx.x*8 + (threadIdx.x >> 5);
    int d0 = (threadIdx.x & 31)*2;
    const float* xr = xin + row*DIN;
    float a0 = in_b[d0], a1 = in_b[d0+1];
    #pragma unroll
    for (int i = 0; i < DIN; i++){
        float xv = xr[i];
        a0 += xv * in_w[i*D_ + d0];
        a1 += xv * in_w[i*D_ + d0 + 1];
    }
    *(unsigned int*)(X + row*D_ + d0) = cvtpk(a0, a1);
}

// ============ K1: fused x-axis spectral conv (fwd+mix+inv), 2 col-slabs/block ====
__global__ __launch_bounds__(256, 3) void k_spec_x(float* __restrict__ ws_f, int layer){
    __shared__ __attribute__((aligned(16))) char lds[49152];
    int t = threadIdx.x, w = t >> 6, lane = t & 63;
    int l15 = lane & 15, l4 = lane >> 4;
    int xcd = blockIdx.x & 7, idx = blockIdx.x >> 3;
    int bb = xcd + 8*(idx >> 6);
    int c  = idx & 63;
    const unsigned short* Xg = (const unsigned short*)((char*)ws_f + WSB_X);
    int mt = w & 1, nt0 = (w >> 1)*2;

    // ---- top prefetch: basis fragments (independent of all barriers) ----
    s16x8 bfA[4];
    {
        const unsigned short* bfg = (const unsigned short*)((char*)ws_f + WSB_BF);
        int kpr = mt*16 + l15;
        #pragma unroll
        for (int ks = 0; ks < 4; ks++)
            bfA[ks] = *(const s16x8*)&bfg[kpr*128 + (l4 + ks*4)*8];
    }
    s16x8 aInv[2];
    {
        const unsigned short* big = (const unsigned short*)((char*)ws_f + WSB_BI);
        #pragma unroll
        for (int mi = 0; mi < 2; mi++){
            int m_ = (w*2 + mi)*16 + l15;
            aInv[mi] = *(const s16x8*)&big[m_*32 + l4*8];
        }
    }

    // ---- P1: stage XsT (transposed [i][m]) for both slabs ----
    for (int s = 0; s < 2; s++){
        long base = (long)bb*1048576 + (long)(c*2 + s)*64;
        char* xst = lds + s*16384;
        #pragma unroll
        for (int it = 0; it < 4; it++){
            int iq = t & 15, np = (t >> 4) + it*16;
            int i0 = iq*4;
            const unsigned int* r0 = (const unsigned int*)(Xg + base + (long)(2*np)*8192 + i0);
            const unsigned int* r1 = (const unsigned int*)(Xg + base + (long)(2*np + 1)*8192 + i0);
            unsigned int a01 = r0[0], a23 = r0[1];
            unsigned int b01 = r1[0], b23 = r1[1];
            unsigned int o0 = __builtin_amdgcn_perm(b01, a01, 0x05040100u);
            unsigned int o1 = __builtin_amdgcn_perm(b01, a01, 0x07060302u);
            unsigned int o2 = __builtin_amdgcn_perm(b23, a23, 0x05040100u);
            unsigned int o3 = __builtin_amdgcn_perm(b23, a23, 0x07060302u);
            *(unsigned int*)(xst + (i0+0)*256 + ((np*4) ^ (((i0+0) & 15) << 4))) = o0;
            *(unsigned int*)(xst + (i0+1)*256 + ((np*4) ^ (((i0+1) & 15) << 4))) = o1;
            *(unsigned int*)(xst + (i0+2)*256 + ((np*4) ^ (((i0+2) & 15) << 4))) = o2;
            *(unsigned int*)(xst + (i0+3)*256 + ((np*4) ^ (((i0+3) & 15) << 4))) = o3;
        }
    }
    __syncthreads();

    // ---- P2: fwd MFMA -> T2p/T2s f16 tables ----
    {
        for (int s = 0; s < 2; s++){
            char* xst = lds + s*16384;
            f32x4 acc[2] = {{0.f,0.f,0.f,0.f},{0.f,0.f,0.f,0.f}};
            #pragma unroll
            for (int ks = 0; ks < 4; ks++){
                #pragma unroll
                for (int nf = 0; nf < 2; nf++){
                    int i = (nt0 + nf)*16 + l15;
                    s16x8 b = *(const s16x8*)(xst + i*256 + (((l4*16) + ks*64) ^ ((i & 15) << 4)));
                    acc[nf] = __builtin_amdgcn_mfma_f32_16x16x32_bf16(bfA[ks], b, acc[nf], 0, 0, 0);
                }
            }
            char* Tp = lds + 32768 + s*8192;
            char* Ts = lds + 32768 + s*8192 + 4096;
            int k0 = mt*8 + l4*2;
            #pragma unroll
            for (int nf = 0; nf < 2; nf++){
                int i = (nt0 + nf)*16 + l15;
                *(unsigned int*)(Tp + k0*256 + ((i*4) ^ ((k0 & 7) << 4)))         = pkh(acc[nf][0], -acc[nf][1]);
                *(unsigned int*)(Ts + k0*256 + ((i*4) ^ ((k0 & 7) << 4)))         = pkh(acc[nf][1],  acc[nf][0]);
                *(unsigned int*)(Tp + (k0+1)*256 + ((i*4) ^ (((k0+1) & 7) << 4))) = pkh(acc[nf][2], -acc[nf][3]);
                *(unsigned int*)(Ts + (k0+1)*256 + ((i*4) ^ (((k0+1) & 7) << 4))) = pkh(acc[nf][3],  acc[nf][2]);
            }
        }
    }
    __syncthreads();

    // ---- P3: mix via fdot2 (pipelined, both slabs share W loads) -> P @ s*5120 ----
    {
        int k = t >> 4, og = t & 15;
        const unsigned int* Wg = (const unsigned int*)((char*)ws_f + WSB_WMIX)
                                 + ((long)(4 + layer)*16 + k)*4096;   // axis=1 (fwx)
        int xork = (k & 7) << 4;
        const char* Tp0 = lds + 32768;
        const char* Ts0 = lds + 36864;
        const char* Tp1 = lds + 40960;
        const char* Ts1 = lds + 45056;
        float pre0[4] = {0,0,0,0}, pim0[4] = {0,0,0,0};
        float pre1[4] = {0,0,0,0}, pim1[4] = {0,0,0,0};
        #pragma unroll 4
        for (int i0 = 0; i0 < 64; i0 += 4){
            u32x4 tp0 = *(const u32x4*)(Tp0 + k*256 + ((i0*4) ^ xork));
            u32x4 ts0 = *(const u32x4*)(Ts0 + k*256 + ((i0*4) ^ xork));
            u32x4 tp1 = *(const u32x4*)(Tp1 + k*256 + ((i0*4) ^ xork));
            u32x4 ts1 = *(const u32x4*)(Ts1 + k*256 + ((i0*4) ^ xork));
            #pragma unroll
            for (int e = 0; e < 4; e++){
                u32x4 wv = *(const u32x4*)&Wg[(i0 + e)*64 + og*4];
                #pragma unroll
                for (int j = 0; j < 4; j++){
                    pre0[j] = fdot2u(tp0[e], wv[j], pre0[j]);
                    pim0[j] = fdot2u(ts0[e], wv[j], pim0[j]);
                    pre1[j] = fdot2u(tp1[e], wv[j], pre1[j]);
                    pim1[j] = fdot2u(ts1[e], wv[j], pim1[j]);
                }
            }
        }
        #pragma unroll
        for (int j = 0; j < 4; j++){
            int o = og*4 + j;
            *(unsigned int*)(lds + o*80 + ((k*4) ^ ((o & 3) << 4)))        = cvtpk(pre0[j], pim0[j]);
            *(unsigned int*)(lds + 5120 + o*80 + ((k*4) ^ ((o & 3) << 4))) = cvtpk(pre1[j], pim1[j]);
        }
    }
    __syncthreads();

    // ---- P4: inv MFMA -> LDS stage (H-pattern) ----
    {
        for (int s = 0; s < 2; s++){
            const char* Ps = lds + s*5120;
            s16x8 bfr[4];
            #pragma unroll
            for (int nt = 0; nt < 4; nt++){
                int o = nt*16 + l15;
                bfr[nt] = *(const s16x8*)(Ps + o*80 + ((l4*16) ^ ((o & 3) << 4)));
            }
            #pragma unroll
            for (int mi = 0; mi < 2; mi++){
                #pragma unroll
                for (int nt = 0; nt < 4; nt++){
                    f32x4 z = {0.f,0.f,0.f,0.f};
                    f32x4 acc = __builtin_amdgcn_mfma_f32_16x16x32_bf16(aInv[mi], bfr[nt], z, 0, 0, 0);
                    int col = s*64 + nt*16 + l15;
                    #pragma unroll
                    for (int q = 0; q < 4; q++){
                        int m = (w*2 + mi)*16 + l4*4 + q;
                        *(unsigned short*)(lds + 10240 + m*256 + (((col >> 3) << 4) ^ ((m & 7) << 4)) + (col & 7)*2) = f2bf(acc[q]);
                    }
                }
            }
        }
    }
    __syncthreads();
    // ---- copyout: per-instruction coalesced (4 rows x 256B per wave-instr) ----
    {
        unsigned short* XSx = (unsigned short*)((char*)ws_f + WSB_XSX);
        int c8 = t & 15, mq = t >> 4;
        #pragma unroll
        for (int j = 0; j < 8; j++){
            int m = mq + j*16;
            u32x4 v = *(const u32x4*)(lds + 10240 + m*256 + ((c8*16) ^ ((m & 7) << 4)));
            *(u32x4*)(XSx + (long)bb*1048576 + (long)m*8192 + c*128 + c8*8) = v;
        }
    }
}

// ============ K2: fused y-axis spectral conv + FeedForward block ============
// Round-10/12 structure (32 KB LDS, 4 blocks/CU) + top-prefetch + pipelined mix
// + per-instruction-coalesced X copyout / XSx prestage.
__global__ __launch_bounds__(256, 4) void k_spec_y_ff(
        float* __restrict__ ws_f, float* __restrict__ out,
        const float* __restrict__ bc_b1, const float* __restrict__ bc_b2,
        const float* __restrict__ fc_b1, int layer, int first){
    __shared__ __attribute__((aligned(16))) char lds[32768];
    int t = threadIdx.x, w = t >> 6, lane = t & 63;
    int l15 = lane & 15, l4 = lane >> 4;
    int xcd = blockIdx.x & 7, idx = blockIdx.x >> 3;     // idx 0..255
    long slab = (long)(xcd + 8*(idx >> 7))*128 + (idx & 127);
    unsigned short* Xg = (unsigned short*)((char*)ws_f + WSB_X);
    long xbase = slab*8192;
    const unsigned short* wb = (const unsigned short*)((char*)ws_f + WSB_WFF);
    int mt = w & 1, nt0 = (w >> 1)*2;

    // ---- top prefetch (issue at t=0; latency hides under P1/P2) ----
    // XSx slab, flat-coalesced: 16B/lane, contiguous per instruction
    u32x4 xvp[4];
    {
        const char* XSxb = (const char*)ws_f + WSB_XSX + slab*16384;
        #pragma unroll
        for (int j = 0; j < 4; j++)
            xvp[j] = *(const u32x4*)(XSxb + j*4096 + t*16);
    }
    // fwd/inv basis fragments
    s16x8 bfF[4];
    {
        const unsigned short* bfg = (const unsigned short*)((char*)ws_f + WSB_BF);
        int kpr = mt*16 + l15;
        #pragma unroll
        for (int ks = 0; ks < 4; ks++)
            bfF[ks] = *(const s16x8*)&bfg[kpr*128 + (l4 + ks*4)*8];
    }
    s16x8 biF[2];
    {
        const unsigned short* big = (const unsigned short*)((char*)ws_f + WSB_BI);
        #pragma unroll
        for (int mi = 0; mi < 2; mi++){
            int n_ = (w*2 + mi)*16 + l15;
            biF[mi] = *(const s16x8*)&big[n_*32 + l4*8];
        }
    }
    // G3 weight fragments (on the critical tail)
    s16x8 fwf[2][8];
    {
        const unsigned short* fw1g = wb + 32768 + (long)layer*8192;
        #pragma unroll
        for (int ks = 0; ks < 2; ks++){
            int kch = l4 + ks*4;
            #pragma unroll
            for (int nf = 0; nf < 8; nf++){
                int n = nf*16 + l15;
                fwf[ks][nf] = *(const s16x8*)&fw1g[n*64 + kch*8];
            }
        }
    }

    // ---- P1: stage XsT transposed [i][n] @0 ----
    #pragma unroll
    for (int it = 0; it < 4; it++){
        int iq = t & 15, np = (t >> 4) + it*16;
        int i0 = iq*4;
        const unsigned int* r0 = (const unsigned int*)(Xg + xbase + (long)(2*np)*64 + i0);
        const unsigned int* r1 = (const unsigned int*)(Xg + xbase + (long)(2*np + 1)*64 + i0);
        unsigned int a01 = r0[0], a23 = r0[1];
        unsigned int b01 = r1[0], b23 = r1[1];
        unsigned int o0 = __builtin_amdgcn_perm(b01, a01, 0x05040100u);
        unsigned int o1 = __builtin_amdgcn_perm(b01, a01, 0x07060302u);
        unsigned int o2 = __builtin_amdgcn_perm(b23, a23, 0x05040100u);
        unsigned int o3 = __builtin_amdgcn_perm(b23, a23, 0x07060302u);
        *(unsigned int*)(lds + (i0+0)*256 + ((np*4) ^ (((i0+0) & 15) << 4))) = o0;
        *(unsigned int*)(lds + (i0+1)*256 + ((np*4) ^ (((i0+1) & 15) << 4))) = o1;
        *(unsigned int*)(lds + (i0+2)*256 + ((np*4) ^ (((i0+2) & 15) << 4))) = o2;
        *(unsigned int*)(lds + (i0+3)*256 + ((np*4) ^ (((i0+3) & 15) << 4))) = o3;
    }
    __syncthreads();

    // ---- P2: fwd MFMA -> T2p @16384 / T2s @20480 ----
    {
        f32x4 acc[2] = {{0.f,0.f,0.f,0.f},{0.f,0.f,0.f,0.f}};
        #pragma unroll
        for (int ks = 0; ks < 4; ks++){
            #pragma unroll
            for (int nf = 0; nf < 2; nf++){
                int i = (nt0 + nf)*16 + l15;
                s16x8 b = *(const s16x8*)(lds + i*256 + (((l4*16) + ks*64) ^ ((i & 15) << 4)));
                acc[nf] = __builtin_amdgcn_mfma_f32_16x16x32_bf16(bfF[ks], b, acc[nf], 0, 0, 0);
            }
        }
        char* Tp = lds + 16384;
        char* Ts = lds + 20480;
        int k0 = mt*8 + l4*2;
        #pragma unroll
        for (int nf = 0; nf < 2; nf++){
            int i = (nt0 + nf)*16 + l15;
            *(unsigned int*)(Tp + k0*256 + ((i*4) ^ ((k0 & 7) << 4)))         = pkh(acc[nf][0], -acc[nf][1]);
            *(unsigned int*)(Ts + k0*256 + ((i*4) ^ ((k0 & 7) << 4)))         = pkh(acc[nf][1],  acc[nf][0]);
            *(unsigned int*)(Tp + (k0+1)*256 + ((i*4) ^ (((k0+1) & 7) << 4))) = pkh(acc[nf][2], -acc[nf][3]);
            *(unsigned int*)(Ts + (k0+1)*256 + ((i*4) ^ (((k0+1) & 7) << 4))) = pkh(acc[nf][3],  acc[nf][2]);
        }
    }
    __syncthreads();

    // ---- P3: mix via fdot2 (pipelined) -> P @24576 ; XSx prestage -> XS @0 ----
    {
        int k = t >> 4, og = t & 15;
        const unsigned int* Wg = (const unsigned int*)((char*)ws_f + WSB_WMIX)
                                 + ((long)layer*16 + k)*4096;
        int xork = (k & 7) << 4;
        const char* Tp = lds + 16384;
        const char* Ts = lds + 20480;
        float pre[4] = {0,0,0,0}, pim[4] = {0,0,0,0};
        #pragma unroll 4
        for (int i0 = 0; i0 < 64; i0 += 4){
            u32x4 tp  = *(const u32x4*)(Tp + k*256 + ((i0*4) ^ xork));
            u32x4 tsv = *(const u32x4*)(Ts + k*256 + ((i0*4) ^ xork));
            #pragma unroll
            for (int e = 0; e < 4; e++){
                u32x4 wv = *(const u32x4*)&Wg[(i0 + e)*64 + og*4];
                #pragma unroll
                for (int j = 0; j < 4; j++){
                    pre[j] = fdot2u(tp[e],  wv[j], pre[j]);
                    pim[j] = fdot2u(tsv[e], wv[j], pim[j]);
                }
            }
        }
        #pragma unroll
        for (int j = 0; j < 4; j++){
            int o = og*4 + j;
            *(unsigned int*)(lds + 24576 + o*80 + ((k*4) ^ ((o & 3) << 4))) = cvtpk(pre[j], pim[j]);
        }
        // XSx prestage stores (XS layout @0; prefetched at top); flat mapping
        int c8 = t & 7, nq = t >> 3;
        #pragma unroll
        for (int j = 0; j < 4; j++){
            int n = nq + j*32;
            *(u32x4*)(lds + n*128 + ((c8*16) ^ ((n & 7) << 4))) = xvp[j];
        }
    }
    __syncthreads();

    // ---- P4: inv MFMA + XSx add (LDS rmw) -> XS bf16 @0 ----
    {
        s16x8 bfr[4];
        #pragma unroll
        for (int nt = 0; nt < 4; nt++){
            int o = nt*16 + l15;
            bfr[nt] = *(const s16x8*)(lds + 24576 + o*80 + ((l4*16) ^ ((o & 3) << 4)));
        }
        #pragma unroll
        for (int mi = 0; mi < 2; mi++){
            #pragma unroll
            for (int nt = 0; nt < 4; nt++){
                f32x4 z = {0.f,0.f,0.f,0.f};
                f32x4 acc = __builtin_amdgcn_mfma_f32_16x16x32_bf16(biF[mi], bfr[nt], z, 0, 0, 0);
                #pragma unroll
                for (int q = 0; q < 4; q++){
                    int nr = (w*2 + mi)*16 + l4*4 + q;
                    int o = nt*16 + l15;
                    char* p = lds + nr*128 + ((o*2) ^ ((nr & 7) << 4));
                    float v = acc[q] + bf2f(*(const unsigned short*)p);
                    *(unsigned short*)p = f2bf(v);
                }
            }
        }
    }
    __syncthreads();

    // ---- P5: XS frags -> regs (shared by G1/G3); bias/head vectors ----
    s16x8 af[2][2];
    #pragma unroll
    for (int rr = 0; rr < 2; rr++)
    #pragma unroll
    for (int ks = 0; ks < 2; ks++){
        int r = w*32 + rr*16 + l15, kch = l4 + ks*4;
        af[rr][ks] = *(const s16x8*)(lds + r*128 + ((kch << 4) ^ ((r & 7) << 4)));
    }
    float bb1v[8], fb1v[8], uv[8], bb2v[4];
    {
        #pragma unroll
        for (int nf = 0; nf < 8; nf++){
            bb1v[nf] = bc_b1[layer*128 + nf*16 + l15];
            fb1v[nf] = fc_b1[layer*128 + nf*16 + l15];
            uv[nf]   = ((const float*)((char*)ws_f + WSB_U))[layer*128 + nf*16 + l15];
        }
        #pragma unroll
        for (int nf = 0; nf < 4; nf++)
            bb2v[nf] = bc_b2[layer*64 + nf*16 + l15];
    }
    float ddv = *((const float*)((char*)ws_f + WSB_D) + layer);
    __syncthreads();

    if (layer != NL-1){
        // ---- G1 (bc): h = relu(xs@w1 + b1) -> H @0 ----
        {
            const unsigned short* w1g = wb + (long)layer*8192;   // [j=128][i=64]
            f32x4 acc[2][8];
            #pragma unroll
            for (int mi = 0; mi < 2; mi++)
            #pragma unroll
            for (int nf = 0; nf < 8; nf++)
                acc[mi][nf] = (f32x4){bb1v[nf], bb1v[nf], bb1v[nf], bb1v[nf]};
            #pragma unroll
            for (int ks = 0; ks < 2; ks++){
                int kch = l4 + ks*4;
                #pragma unroll
                for (int nf = 0; nf < 8; nf++){
                    int n = nf*16 + l15;
                    s16x8 b = *(const s16x8*)&w1g[n*64 + kch*8];
                    acc[0][nf] = __builtin_amdgcn_mfma_f32_16x16x32_bf16(af[0][ks], b, acc[0][nf], 0, 0, 0);
                    acc[1][nf] = __builtin_amdgcn_mfma_f32_16x16x32_bf16(af[1][ks], b, acc[1][nf], 0, 0, 0);
                }
            }
            #pragma unroll
            for (int mi = 0; mi < 2; mi++)
            #pragma unroll
            for (int nf = 0; nf < 8; nf++){
                int ncol = nf*16 + l15;
                #pragma unroll
                for (int q = 0; q < 4; q++){
                    int mrow = w*32 + mi*16 + l4*4 + q;
                    float hv = fmaxf(acc[mi][nf][q], 0.f);
                    *(unsigned short*)(lds + mrow*256 + (((ncol >> 3) << 4) ^ ((mrow & 7) << 4)) + (ncol & 7)*2) = f2bf(hv);
                }
            }
        }
        __syncthreads();

        // ---- G2: xnew = x_old - (h@w2 + b2); x_old from global (L2-hot) ----
        unsigned int xnpk2[2][4][2];
        {
            const unsigned short* w2g = wb + 65536 + (long)layer*8192;  // [o=64][j=128]
            unsigned short xo[2][4][4];
            #pragma unroll
            for (int mi = 0; mi < 2; mi++)
            #pragma unroll
            for (int nf = 0; nf < 4; nf++)
            #pragma unroll
            for (int q = 0; q < 4; q++){
                int mrow = w*32 + mi*16 + l4*4 + q;
                xo[mi][nf][q] = Xg[xbase + (long)mrow*64 + nf*16 + l15];
            }
            f32x4 acc[2][4];
            #pragma unroll
            for (int mi = 0; mi < 2; mi++)
            #pragma unroll
            for (int nf = 0; nf < 4; nf++)
                acc[mi][nf] = (f32x4){bb2v[nf], bb2v[nf], bb2v[nf], bb2v[nf]};
            #pragma unroll
            for (int ks = 0; ks < 4; ks++){
                int kch = l4 + ks*4;
                int r0 = w*32 + l15, r1 = w*32 + 16 + l15;
                s16x8 a0 = *(const s16x8*)(lds + r0*256 + ((kch << 4) ^ ((r0 & 7) << 4)));
                s16x8 a1 = *(const s16x8*)(lds + r1*256 + ((kch << 4) ^ ((r1 & 7) << 4)));
                #pragma unroll
                for (int nf = 0; nf < 4; nf++){
                    int n = nf*16 + l15;
                    s16x8 b = *(const s16x8*)&w2g[n*128 + kch*8];
                    acc[0][nf] = __builtin_amdgcn_mfma_f32_16x16x32_bf16(a0, b, acc[0][nf], 0, 0, 0);
                    acc[1][nf] = __builtin_amdgcn_mfma_f32_16x16x32_bf16(a1, b, acc[1][nf], 0, 0, 0);
                }
            }
            #pragma unroll
            for (int mi = 0; mi < 2; mi++)
            #pragma unroll
            for (int nf = 0; nf < 4; nf++){
                float xn[4];
                #pragma unroll
                for (int q = 0; q < 4; q++)
                    xn[q] = bf2f(xo[mi][nf][q]) - acc[mi][nf][q];
                xnpk2[mi][nf][0] = cvtpk(xn[0], xn[1]);
                xnpk2[mi][nf][1] = cvtpk(xn[2], xn[3]);
            }
        }
        __syncthreads();
        // ---- stage Xnew @0 (T-pattern, over dead H) ----
        #pragma unroll
        for (int mi = 0; mi < 2; mi++)
        #pragma unroll
        for (int nf = 0; nf < 4; nf++){
            int ncol = nf*16 + l15;
            #pragma unroll
            for (int q = 0; q < 4; q++){
                int mrow = w*32 + mi*16 + l4*4 + q;
                unsigned int pk = xnpk2[mi][nf][q >> 1];
                unsigned short v = (q & 1) ? (unsigned short)(pk >> 16) : (unsigned short)(pk & 0xffffu);
                *(unsigned short*)(lds + mrow*128 + ((ncol*2) ^ ((mrow & 7) << 4))) = v;
            }
        }
        __syncthreads();
        // ---- copyout X: per-instruction coalesced (1 KB contiguous per wave-instr) ----
        {
            int c8 = t & 7, nq = t >> 3;
            #pragma unroll
            for (int j = 0; j < 4; j++){
                int n = nq + j*32;
                u32x4 v = *(const u32x4*)(lds + n*128 + ((c8*16) ^ ((n & 7) << 4)));
                *(u32x4*)(Xg + xbase + n*64 + c8*8) = v;
            }
        }
    }

    // ---- G3 (fc): h2 = relu(xs@fw1 + fb1); head from accumulators ----
    {
        f32x4 acc[2][8];
        #pragma unroll
        for (int mi = 0; mi < 2; mi++)
        #pragma unroll
        for (int nf = 0; nf < 8; nf++)
            acc[mi][nf] = (f32x4){fb1v[nf], fb1v[nf], fb1v[nf], fb1v[nf]};
        #pragma unroll
        for (int ks = 0; ks < 2; ks++){
            #pragma unroll
            for (int nf = 0; nf < 8; nf++){
                acc[0][nf] = __builtin_amdgcn_mfma_f32_16x16x32_bf16(af[0][ks], fwf[ks][nf], acc[0][nf], 0, 0, 0);
                acc[1][nf] = __builtin_amdgcn_mfma_f32_16x16x32_bf16(af[1][ks], fwf[ks][nf], acc[1][nf], 0, 0, 0);
            }
        }
        #pragma unroll
        for (int mi = 0; mi < 2; mi++)
        #pragma unroll
        for (int q = 0; q < 4; q++){
            float s = 0.f;
            #pragma unroll
            for (int nf = 0; nf < 8; nf++)
                s += fmaxf(acc[mi][nf][q], 0.f) * uv[nf];
            s += __shfl_xor(s, 1);
            s += __shfl_xor(s, 2);
            s += __shfl_xor(s, 4);
            s += __shfl_xor(s, 8);
            if (l15 == 0){
                int r = w*32 + mi*16 + l4*4 + q;
                long g = slab*128 + r;
                float fo = s + ddv;
                out[g] = first ? fo : (out[g] + fo);
            }
        }
    }
}

// ============ host launch ============
extern "C" void kernel_launch(void* const* d_in, const int* in_sizes, int n_in,
                              void* d_out, int out_size, void* d_ws, size_t ws_size,
                              hipStream_t stream){
    if (ws_size < (size_t)WS_NEEDED) return;
    const float* xin    = (const float*)d_in[0];
    const float* in_w   = (const float*)d_in[1];
    const float* in_b   = (const float*)d_in[2];
    const float* fwy_re = (const float*)d_in[3];
    const float* fwy_im = (const float*)d_in[4];
    const float* fwx_re = (const float*)d_in[5];
    const float* fwx_im = (const float*)d_in[6];
    const float* bc_w1  = (const float*)d_in[7];
    const float* bc_b1  = (const float*)d_in[8];
    const float* bc_w2  = (const float*)d_in[9];
    const float* bc_b2  = (const float*)d_in[10];
    const float* fc_w1  = (const float*)d_in[11];
    const float* fc_b1  = (const float*)d_in[12];
    const float* fc_w2  = (const float*)d_in[13];
    const float* fc_b2  = (const float*)d_in[14];
    const float* out_w1 = (const float*)d_in[15];
    const float* out_b1 = (const float*)d_in[16];
    const float* out_w2 = (const float*)d_in[17];
    const float* out_b2 = (const float*)d_in[18];
    float* ws  = (float*)d_ws;
    float* out = (float*)d_out;

    k_init<<<1, 256, 0, stream>>>(out_w1, out_b1, out_w2, out_b2, fc_w2, fc_b2, ws);
    k_wconv<<<384, 256, 0, stream>>>(bc_w1, fc_w1, bc_w2, ws);
    k_wmix<<<2048, 256, 0, stream>>>(fwy_re, fwy_im, fwx_re, fwx_im, ws);
    k_embed<<<32768, 256, 0, stream>>>(xin, in_w, in_b, (unsigned short*)((char*)ws + WSB_X));

    for (int l = 0; l < NL; l++){
        k_spec_x<<<1024, 256, 0, stream>>>(ws, l);
        k_spec_y_ff<<<2048, 256, 0, stream>>>(ws, out, bc_b1, bc_b2, fc_b1, l, l == 0 ? 1 : 0);
    }
}

// Round 14
// 498.458 us; speedup vs baseline: 1.3620x; 1.3620x over previous
//
#include <hip/hip_runtime.h>

// ---------------- problem constants ----------------
#define B_    16
#define M_    128
#define N_    128
#define DIN   12
#define D_    64
#define H_    128
#define MODES 16
#define NL    4
#define NPIX  262144       // B*M*N

typedef float  f32x2 __attribute__((ext_vector_type(2)));
typedef float  f32x4 __attribute__((ext_vector_type(4)));
typedef short  s16x8 __attribute__((ext_vector_type(8)));
typedef unsigned int u32x2 __attribute__((ext_vector_type(2)));
typedef unsigned int u32x4 __attribute__((ext_vector_type(4)));
typedef __fp16 h16x2 __attribute__((ext_vector_type(2)));   // matches cvt_pkrtz / fdot2

// ---------------- workspace layout (BYTE offsets) ----------------
#define WSB_X      0L           // bf16 X [B][M][N][64]           33554432
#define WSB_XSX    33554432L    // bf16 XSx [b][m][nc][o]         33554432
#define WSB_BF     67108864L    // fwd basis bf16 [kp=32][n=128]  8192
#define WSB_BI     67117056L    // inv basis bf16 [n=128][kp=32]  8192
#define WSB_U      67125248L    // u[4][128] f32                  2048
#define WSB_D      67127296L    // d[4] f32 (+pad)                16
#define WSB_WFF    67127312L    // FF weights bf16 (3x4x8192 u16) 196608
#define WSB_WMIX   67323920L    // mix weights u32 = f16(re,im) [ax][l][k][i][o] 2097152
#define WS_NEEDED  69421072L

__device__ __forceinline__ unsigned short f2bf(float f){
    unsigned int u = __float_as_uint(f);
    u += 0x7fffu + ((u >> 16) & 1u);
    return (unsigned short)(u >> 16);
}
__device__ __forceinline__ float bf2f(unsigned short s){
    return __uint_as_float(((unsigned int)s) << 16);
}
__device__ __forceinline__ unsigned int cvtpk(float lo, float hi){   // f32x2 -> bf16x2
    unsigned int r;
    asm("v_cvt_pk_bf16_f32 %0, %1, %2" : "=v"(r) : "v"(lo), "v"(hi));
    return r;
}
__device__ __forceinline__ unsigned int pkh(float lo, float hi){     // f32x2 -> f16x2
    h16x2 h = __builtin_amdgcn_cvt_pkrtz(lo, hi);
    return __builtin_bit_cast(unsigned int, h);
}
__device__ __forceinline__ float fdot2u(unsigned int a, unsigned int b, float c){
    h16x2 ha = __builtin_bit_cast(h16x2, a);
    h16x2 hb = __builtin_bit_cast(h16x2, b);
    return __builtin_amdgcn_fdot2(ha, hb, c, false);
}

// ============ init: bf16 basis tables + collapsed output head ============
__global__ void k_init(const float* __restrict__ out_w1, const float* __restrict__ out_b1,
                       const float* __restrict__ out_w2, const float* __restrict__ out_b2,
                       const float* __restrict__ fc_w2, const float* __restrict__ fc_b2,
                       float* __restrict__ ws){
    __shared__ float v_s[64];
    __shared__ float c_s;
    int t = threadIdx.x;
    if (t < 64){
        float a = 0.f;
        for (int j = 0; j < H_; j++) a += out_w1[t*H_ + j] * out_w2[j];
        v_s[t] = a;
    }
    if (t == 64){
        float a = 0.f;
        for (int j = 0; j < H_; j++) a += out_b1[j] * out_w2[j];
        c_s = a + out_b2[0];
    }
    __syncthreads();
    float* uw = (float*)((char*)ws + WSB_U);
    float* dw = (float*)((char*)ws + WSB_D);
    if (t < 128){
        for (int l = 0; l < NL; l++){
            float a = 0.f;
            for (int o = 0; o < D_; o++) a += fc_w2[(l*H_ + t)*D_ + o] * v_s[o];
            uw[l*128 + t] = a;
        }
    }
    if (t >= 128 && t < 132){
        int l = t - 128;
        float a = 0.f;
        for (int o = 0; o < D_; o++) a += fc_b2[l*D_ + o] * v_s[o];
        dw[l] = a + c_s;
    }
    const float isn = 0.08838834764831845f;  // 1/sqrt(128)
    unsigned short* bft = (unsigned short*)((char*)ws + WSB_BF);
    unsigned short* bit = (unsigned short*)((char*)ws + WSB_BI);
    for (int e = t; e < 4096; e += 256){
        { int kp = e >> 7, n = e & 127, k = kp >> 1;
          float ang = 6.283185307179586f * (float)((k*n) & 127) / 128.0f;
          bft[e] = f2bf((kp & 1) ? (-sinf(ang)*isn) : (cosf(ang)*isn)); }
        { int n = e >> 5, kp = e & 31, k = kp >> 1;
          float ang = 6.283185307179586f * (float)((k*n) & 127) / 128.0f;
          float val;
          if (kp & 1) val = (k == 0) ? 0.f : (-2.f*sinf(ang)*isn);
          else        val = ((k == 0) ? 1.f : 2.f) * cosf(ang) * isn;
          bit[e] = f2bf(val); }
    }
}

// ============ FF weights -> bf16 transposed ============
__global__ void k_wconv(const float* __restrict__ bc_w1, const float* __restrict__ fc_w1,
                        const float* __restrict__ bc_w2, float* __restrict__ ws){
    unsigned short* wb = (unsigned short*)((char*)ws + WSB_WFF);
    int e = blockIdx.x*256 + threadIdx.x;      // < 98304
    int a = e >> 15;
    int r = e & 32767;
    int l = r >> 13;
    int q = r & 8191;
    if (a == 0){
        int j = q >> 6, i = q & 63;
        wb[e] = f2bf(bc_w1[(l*D_ + i)*H_ + j]);
    } else if (a == 1){
        int j = q >> 6, i = q & 63;
        wb[e] = f2bf(fc_w1[(l*D_ + i)*H_ + j]);
    } else {
        int o = q >> 7, j = q & 127;
        wb[e] = f2bf(bc_w2[(l*H_ + j)*D_ + o]);
    }
}

// ============ mix weights -> packed f16 u32 (re,im) [ax][l][k][i][o] ============
__global__ void k_wmix(const float* __restrict__ fwy_re, const float* __restrict__ fwy_im,
                       const float* __restrict__ fwx_re, const float* __restrict__ fwx_im,
                       float* __restrict__ ws){
    unsigned int* wm = (unsigned int*)((char*)ws + WSB_WMIX);
    int e = blockIdx.x*256 + threadIdx.x;   // < 524288
    int ax = e >> 18;
    int r  = e & 262143;
    int l  = r >> 16;
    int k  = (r >> 12) & 15;
    int i  = (r >> 6) & 63;
    int o  = r & 63;
    long sidx = (((long)l*64 + i)*64 + o)*16 + k;
    float re = ax ? fwx_re[sidx] : fwy_re[sidx];
    float im = ax ? fwx_im[sidx] : fwy_im[sidx];
    wm[e] = pkh(re, im);
}

// ============ input embedding -> bf16 X ============
__global__ __launch_bounds__(256) void k_embed(const float* __restrict__ xin,
                                               const float* __restrict__ in_w,
                                               const float* __restrict__ in_b,
                                               unsigned short* __restrict__ X){
    long row = (long)blockIdx.x*8 + (threadIdx.x >> 5);
    int d0 = (threadIdx.x & 31)*2;
    const float* xr = xin + row*DIN;
    float a0 = in_b[d0], a1 = in_b[d0+1];
    #pragma unroll
    for (int i = 0; i < DIN; i++){
        float xv = xr[i];
        a0 += xv * in_w[i*D_ + d0];
        a1 += xv * in_w[i*D_ + d0 + 1];
    }
    *(unsigned int*)(X + row*D_ + d0) = cvtpk(a0, a1);
}

// ============ K1: fused x-axis spectral conv (round-12 verbatim) ============
__global__ __launch_bounds__(256, 3) void k_spec_x(float* __restrict__ ws_f, int layer){
    __shared__ __attribute__((aligned(16))) char lds[49152];
    int t = threadIdx.x, w = t >> 6, lane = t & 63;
    int l15 = lane & 15, l4 = lane >> 4;
    int xcd = blockIdx.x & 7, idx = blockIdx.x >> 3;
    int bb = xcd + 8*(idx >> 6);
    int c  = idx & 63;
    const unsigned short* Xg = (const unsigned short*)((char*)ws_f + WSB_X);

    // ---- P1: stage XsT (transposed [i][m]) for both slabs ----
    for (int s = 0; s < 2; s++){
        long base = (long)bb*1048576 + (long)(c*2 + s)*64;
        char* xst = lds + s*16384;
        #pragma unroll
        for (int it = 0; it < 4; it++){
            int iq = t & 15, np = (t >> 4) + it*16;
            int i0 = iq*4;
            const unsigned int* r0 = (const unsigned int*)(Xg + base + (long)(2*np)*8192 + i0);
            const unsigned int* r1 = (const unsigned int*)(Xg + base + (long)(2*np + 1)*8192 + i0);
            unsigned int a01 = r0[0], a23 = r0[1];
            unsigned int b01 = r1[0], b23 = r1[1];
            unsigned int o0 = __builtin_amdgcn_perm(b01, a01, 0x05040100u);
            unsigned int o1 = __builtin_amdgcn_perm(b01, a01, 0x07060302u);
            unsigned int o2 = __builtin_amdgcn_perm(b23, a23, 0x05040100u);
            unsigned int o3 = __builtin_amdgcn_perm(b23, a23, 0x07060302u);
            *(unsigned int*)(xst + (i0+0)*256 + ((np*4) ^ (((i0+0) & 15) << 4))) = o0;
            *(unsigned int*)(xst + (i0+1)*256 + ((np*4) ^ (((i0+1) & 15) << 4))) = o1;
            *(unsigned int*)(xst + (i0+2)*256 + ((np*4) ^ (((i0+2) & 15) << 4))) = o2;
            *(unsigned int*)(xst + (i0+3)*256 + ((np*4) ^ (((i0+3) & 15) << 4))) = o3;
        }
    }
    __syncthreads();

    // ---- P2: fwd MFMA (Bf A-frags from global) -> T2p/T2s f16 tables ----
    int mt = w & 1, nt0 = (w >> 1)*2;
    {
        const unsigned short* bfg = (const unsigned short*)((char*)ws_f + WSB_BF);
        int kpr = mt*16 + l15;
        s16x8 bfA[4];
        #pragma unroll
        for (int ks = 0; ks < 4; ks++)
            bfA[ks] = *(const s16x8*)&bfg[kpr*128 + (l4 + ks*4)*8];
        for (int s = 0; s < 2; s++){
            char* xst = lds + s*16384;
            f32x4 acc[2] = {{0.f,0.f,0.f,0.f},{0.f,0.f,0.f,0.f}};
            #pragma unroll
            for (int ks = 0; ks < 4; ks++){
                #pragma unroll
                for (int nf = 0; nf < 2; nf++){
                    int i = (nt0 + nf)*16 + l15;
                    s16x8 b = *(const s16x8*)(xst + i*256 + (((l4*16) + ks*64) ^ ((i & 15) << 4)));
                    acc[nf] = __builtin_amdgcn_mfma_f32_16x16x32_bf16(bfA[ks], b, acc[nf], 0, 0, 0);
                }
            }
            char* Tp = lds + 32768 + s*8192;
            char* Ts = lds + 32768 + s*8192 + 4096;
            int k0 = mt*8 + l4*2;
            #pragma unroll
            for (int nf = 0; nf < 2; nf++){
                int i = (nt0 + nf)*16 + l15;
                *(unsigned int*)(Tp + k0*256 + ((i*4) ^ ((k0 & 7) << 4)))         = pkh(acc[nf][0], -acc[nf][1]);
                *(unsigned int*)(Ts + k0*256 + ((i*4) ^ ((k0 & 7) << 4)))         = pkh(acc[nf][1],  acc[nf][0]);
                *(unsigned int*)(Tp + (k0+1)*256 + ((i*4) ^ (((k0+1) & 7) << 4))) = pkh(acc[nf][2], -acc[nf][3]);
                *(unsigned int*)(Ts + (k0+1)*256 + ((i*4) ^ (((k0+1) & 7) << 4))) = pkh(acc[nf][3],  acc[nf][2]);
            }
        }
    }
    __syncthreads();

    // ---- P3: mix via fdot2 (both slabs share W loads) -> P @ s*5120 ----
    {
        int k = t >> 4, og = t & 15;
        const unsigned int* Wg = (const unsigned int*)((char*)ws_f + WSB_WMIX)
                                 + ((long)(4 + layer)*16 + k)*4096;   // axis=1 (fwx)
        int xork = (k & 7) << 4;
        const char* Tp0 = lds + 32768;
        const char* Ts0 = lds + 36864;
        const char* Tp1 = lds + 40960;
        const char* Ts1 = lds + 45056;
        float pre0[4] = {0,0,0,0}, pim0[4] = {0,0,0,0};
        float pre1[4] = {0,0,0,0}, pim1[4] = {0,0,0,0};
        for (int i0 = 0; i0 < 64; i0 += 4){
            u32x4 tp0 = *(const u32x4*)(Tp0 + k*256 + ((i0*4) ^ xork));
            u32x4 ts0 = *(const u32x4*)(Ts0 + k*256 + ((i0*4) ^ xork));
            u32x4 tp1 = *(const u32x4*)(Tp1 + k*256 + ((i0*4) ^ xork));
            u32x4 ts1 = *(const u32x4*)(Ts1 + k*256 + ((i0*4) ^ xork));
            #pragma unroll
            for (int e = 0; e < 4; e++){
                u32x4 wv = *(const u32x4*)&Wg[(i0 + e)*64 + og*4];
                #pragma unroll
                for (int j = 0; j < 4; j++){
                    pre0[j] = fdot2u(tp0[e], wv[j], pre0[j]);
                    pim0[j] = fdot2u(ts0[e], wv[j], pim0[j]);
                    pre1[j] = fdot2u(tp1[e], wv[j], pre1[j]);
                    pim1[j] = fdot2u(ts1[e], wv[j], pim1[j]);
                }
            }
        }
        #pragma unroll
        for (int j = 0; j < 4; j++){
            int o = og*4 + j;
            *(unsigned int*)(lds + o*80 + ((k*4) ^ ((o & 3) << 4)))        = cvtpk(pre0[j], pim0[j]);
            *(unsigned int*)(lds + 5120 + o*80 + ((k*4) ^ ((o & 3) << 4))) = cvtpk(pre1[j], pim1[j]);
        }
    }
    __syncthreads();

    // ---- P4: inv MFMA -> LDS stage (H-pattern) ----
    {
        const unsigned short* big = (const unsigned short*)((char*)ws_f + WSB_BI);
        s16x8 aInv[2];
        #pragma unroll
        for (int mi = 0; mi < 2; mi++){
            int m_ = (w*2 + mi)*16 + l15;
            aInv[mi] = *(const s16x8*)&big[m_*32 + l4*8];
        }
        for (int s = 0; s < 2; s++){
            const char* Ps = lds + s*5120;
            s16x8 bfr[4];
            #pragma unroll
            for (int nt = 0; nt < 4; nt++){
                int o = nt*16 + l15;
                bfr[nt] = *(const s16x8*)(Ps + o*80 + ((l4*16) ^ ((o & 3) << 4)));
            }
            #pragma unroll
            for (int mi = 0; mi < 2; mi++){
                #pragma unroll
                for (int nt = 0; nt < 4; nt++){
                    f32x4 z = {0.f,0.f,0.f,0.f};
                    f32x4 acc = __builtin_amdgcn_mfma_f32_16x16x32_bf16(aInv[mi], bfr[nt], z, 0, 0, 0);
                    int col = s*64 + nt*16 + l15;
                    #pragma unroll
                    for (int q = 0; q < 4; q++){
                        int m = (w*2 + mi)*16 + l4*4 + q;
                        *(unsigned short*)(lds + 10240 + m*256 + (((col >> 3) << 4) ^ ((m & 7) << 4)) + (col & 7)*2) = f2bf(acc[q]);
                    }
                }
            }
        }
    }
    __syncthreads();
    // ---- copyout: 128B/thread contiguous ----
    {
        unsigned short* XSx = (unsigned short*)((char*)ws_f + WSB_XSX);
        int m = t >> 1, half = t & 1;
        long gb = (long)bb*1048576 + (long)m*8192 + c*128 + half*64;
        const char* src = lds + 10240 + m*256;
        #pragma unroll
        for (int j = 0; j < 8; j++){
            int ch = half*8 + j;
            u32x4 v = *(const u32x4*)(src + ((ch*16) ^ ((m & 7) << 4)));
            *(u32x4*)(XSx + gb + j*8) = v;
        }
    }
}

// ============ K2: fused y-axis spectral conv + FF (LDS-staged weights) ============
// LDS map (49152 B, 3 blocks/CU):
//   @0:     XsT(16K)[P1] -> XS @0 [P3 prestage; P4 rmw; P5 r] -> H @0..32767 [G1 w; G2 r]
//           -> Xstage @0 (16K) [post-G2 w; copyout r]
//   @16384: T2p(4K) [P2 w; P3 r]; @20480: T2s(4K); @24576: P(5K) [P3 w; P4 r]
//           (all dead after P4 -> H overlays)
//   @32768: Wstage(16K): w1 [P1 w; G1 r] -> w2 [stage; G2 r] -> fw1 [stage; G3 r]
__global__ __launch_bounds__(256, 3) void k_spec_y_ff(
        float* __restrict__ ws_f, float* __restrict__ out,
        const float* __restrict__ bc_b1, const float* __restrict__ bc_b2,
        const float* __restrict__ fc_b1, int layer, int first){
    __shared__ __attribute__((aligned(16))) char lds[49152];
    int t = threadIdx.x, w = t >> 6, lane = t & 63;
    int l15 = lane & 15, l4 = lane >> 4;
    int xcd = blockIdx.x & 7, idx = blockIdx.x >> 3;     // idx 0..255
    long slab = (long)(xcd + 8*(idx >> 7))*128 + (idx & 127);
    unsigned short* Xg = (unsigned short*)((char*)ws_f + WSB_X);
    long xbase = slab*8192;
    const unsigned short* wb = (const unsigned short*)((char*)ws_f + WSB_WFF);
    int last = (layer == NL-1);

    // ---- P1: stage XsT transposed [i][n] @0 ; stage first weight table @32768 ----
    #pragma unroll
    for (int it = 0; it < 4; it++){
        int iq = t & 15, np = (t >> 4) + it*16;
        int i0 = iq*4;
        const unsigned int* r0 = (const unsigned int*)(Xg + xbase + (long)(2*np)*64 + i0);
        const unsigned int* r1 = (const unsigned int*)(Xg + xbase + (long)(2*np + 1)*64 + i0);
        unsigned int a01 = r0[0], a23 = r0[1];
        unsigned int b01 = r1[0], b23 = r1[1];
        unsigned int o0 = __builtin_amdgcn_perm(b01, a01, 0x05040100u);
        unsigned int o1 = __builtin_amdgcn_perm(b01, a01, 0x07060302u);
        unsigned int o2 = __builtin_amdgcn_perm(b23, a23, 0x05040100u);
        unsigned int o3 = __builtin_amdgcn_perm(b23, a23, 0x07060302u);
        *(unsigned int*)(lds + (i0+0)*256 + ((np*4) ^ (((i0+0) & 15) << 4))) = o0;
        *(unsigned int*)(lds + (i0+1)*256 + ((np*4) ^ (((i0+1) & 15) << 4))) = o1;
        *(unsigned int*)(lds + (i0+2)*256 + ((np*4) ^ (((i0+2) & 15) << 4))) = o2;
        *(unsigned int*)(lds + (i0+3)*256 + ((np*4) ^ (((i0+3) & 15) << 4))) = o3;
    }
    {
        // layer<3: bc_w1 [j=128][i=64]; layer 3: fc_w1 (only GEMM needed)
        const u32x4* src = (const u32x4*)(wb + (last ? 32768 : 0) + (long)layer*8192);
        for (int cq = t; cq < 1024; cq += 256){
            int r = cq >> 3, c8 = cq & 7;
            *(u32x4*)(lds + 32768 + r*128 + ((c8 << 4) ^ ((r & 7) << 4))) = src[cq];
        }
    }
    __syncthreads();

    // ---- P2: fwd MFMA (Bf A-frags from global) -> T2p @16384 / T2s @20480 ----
    int mt = w & 1, nt0 = (w >> 1)*2;
    {
        const unsigned short* bfg = (const unsigned short*)((char*)ws_f + WSB_BF);
        int kpr = mt*16 + l15;
        f32x4 acc[2] = {{0.f,0.f,0.f,0.f},{0.f,0.f,0.f,0.f}};
        #pragma unroll
        for (int ks = 0; ks < 4; ks++){
            s16x8 a = *(const s16x8*)&bfg[kpr*128 + (l4 + ks*4)*8];
            #pragma unroll
            for (int nf = 0; nf < 2; nf++){
                int i = (nt0 + nf)*16 + l15;
                s16x8 b = *(const s16x8*)(lds + i*256 + (((l4*16) + ks*64) ^ ((i & 15) << 4)));
                acc[nf] = __builtin_amdgcn_mfma_f32_16x16x32_bf16(a, b, acc[nf], 0, 0, 0);
            }
        }
        char* Tp = lds + 16384;
        char* Ts = lds + 20480;
        int k0 = mt*8 + l4*2;
        #pragma unroll
        for (int nf = 0; nf < 2; nf++){
            int i = (nt0 + nf)*16 + l15;
            *(unsigned int*)(Tp + k0*256 + ((i*4) ^ ((k0 & 7) << 4)))         = pkh(acc[nf][0], -acc[nf][1]);
            *(unsigned int*)(Ts + k0*256 + ((i*4) ^ ((k0 & 7) << 4)))         = pkh(acc[nf][1],  acc[nf][0]);
            *(unsigned int*)(Tp + (k0+1)*256 + ((i*4) ^ (((k0+1) & 7) << 4))) = pkh(acc[nf][2], -acc[nf][3]);
            *(unsigned int*)(Ts + (k0+1)*256 + ((i*4) ^ (((k0+1) & 7) << 4))) = pkh(acc[nf][3],  acc[nf][2]);
        }
    }
    __syncthreads();

    // ---- P3: mix via fdot2 -> P @24576 ; XSx prestage -> XS tile @0 (XsT dead) ----
    {
        const unsigned short* XSxg = (const unsigned short*)((char*)ws_f + WSB_XSX) + slab*8192;
        int nr = t >> 1, half = t & 1;
        const unsigned short* srcx = XSxg + nr*64 + half*32;
        u32x4 xv0 = *(const u32x4*)(srcx);
        u32x4 xv1 = *(const u32x4*)(srcx + 8);
        u32x4 xv2 = *(const u32x4*)(srcx + 16);
        u32x4 xv3 = *(const u32x4*)(srcx + 24);

        int k = t >> 4, og = t & 15;
        const unsigned int* Wg = (const unsigned int*)((char*)ws_f + WSB_WMIX)
                                 + ((long)layer*16 + k)*4096;
        int xork = (k & 7) << 4;
        const char* Tp = lds + 16384;
        const char* Ts = lds + 20480;
        float pre[4] = {0,0,0,0}, pim[4] = {0,0,0,0};
        for (int i0 = 0; i0 < 64; i0 += 4){
            u32x4 tp  = *(const u32x4*)(Tp + k*256 + ((i0*4) ^ xork));
            u32x4 tsv = *(const u32x4*)(Ts + k*256 + ((i0*4) ^ xork));
            #pragma unroll
            for (int e = 0; e < 4; e++){
                u32x4 wv = *(const u32x4*)&Wg[(i0 + e)*64 + og*4];
                #pragma unroll
                for (int j = 0; j < 4; j++){
                    pre[j] = fdot2u(tp[e],  wv[j], pre[j]);
                    pim[j] = fdot2u(tsv[e], wv[j], pim[j]);
                }
            }
        }
        #pragma unroll
        for (int j = 0; j < 4; j++){
            int o = og*4 + j;
            *(unsigned int*)(lds + 24576 + o*80 + ((k*4) ^ ((o & 3) << 4))) = cvtpk(pre[j], pim[j]);
        }
        char* dstrow = lds + nr*128;
        int xr = (nr & 7) << 4;
        *(u32x4*)(dstrow + ((half*64 +  0) ^ xr)) = xv0;
        *(u32x4*)(dstrow + ((half*64 + 16) ^ xr)) = xv1;
        *(u32x4*)(dstrow + ((half*64 + 32) ^ xr)) = xv2;
        *(u32x4*)(dstrow + ((half*64 + 48) ^ xr)) = xv3;
    }
    __syncthreads();

    // ---- P4: inv MFMA + XSx add (LDS rmw) -> XS bf16 @0 ----
    {
        const unsigned short* big = (const unsigned short*)((char*)ws_f + WSB_BI);
        s16x8 bfr[4];
        #pragma unroll
        for (int nt = 0; nt < 4; nt++){
            int o = nt*16 + l15;
            bfr[nt] = *(const s16x8*)(lds + 24576 + o*80 + ((l4*16) ^ ((o & 3) << 4)));
        }
        #pragma unroll
        for (int mi = 0; mi < 2; mi++){
            int n_ = (w*2 + mi)*16 + l15;
            s16x8 a = *(const s16x8*)&big[n_*32 + l4*8];
            #pragma unroll
            for (int nt = 0; nt < 4; nt++){
                f32x4 z = {0.f,0.f,0.f,0.f};
                f32x4 acc = __builtin_amdgcn_mfma_f32_16x16x32_bf16(a, bfr[nt], z, 0, 0, 0);
                #pragma unroll
                for (int q = 0; q < 4; q++){
                    int nr = (w*2 + mi)*16 + l4*4 + q;
                    int o = nt*16 + l15;
                    char* p = lds + nr*128 + ((o*2) ^ ((nr & 7) << 4));
                    float v = acc[q] + bf2f(*(const unsigned short*)p);
                    *(unsigned short*)p = f2bf(v);
                }
            }
        }
    }
    __syncthreads();

    // ---- P5: XS frags -> regs (shared by G1/G3); bias/head vectors ----
    s16x8 af[2][2];
    #pragma unroll
    for (int rr = 0; rr < 2; rr++)
    #pragma unroll
    for (int ks = 0; ks < 2; ks++){
        int r = w*32 + rr*16 + l15, kch = l4 + ks*4;
        af[rr][ks] = *(const s16x8*)(lds + r*128 + ((kch << 4) ^ ((r & 7) << 4)));
    }
    float bb1v[8], fb1v[8], uv[8], bb2v[4];
    {
        #pragma unroll
        for (int nf = 0; nf < 8; nf++){
            bb1v[nf] = bc_b1[layer*128 + nf*16 + l15];
            fb1v[nf] = fc_b1[layer*128 + nf*16 + l15];
            uv[nf]   = ((const float*)((char*)ws_f + WSB_U))[layer*128 + nf*16 + l15];
        }
        #pragma unroll
        for (int nf = 0; nf < 4; nf++)
            bb2v[nf] = bc_b2[layer*64 + nf*16 + l15];
    }
    float ddv = *((const float*)((char*)ws_f + WSB_D) + layer);
    __syncthreads();

    if (!last){
        // ---- G1 (bc): h = relu(xs@w1 + b1) -> H @0  (w1 from LDS @32768) ----
        {
            f32x4 acc[2][8];
            #pragma unroll
            for (int mi = 0; mi < 2; mi++)
            #pragma unroll
            for (int nf = 0; nf < 8; nf++)
                acc[mi][nf] = (f32x4){bb1v[nf], bb1v[nf], bb1v[nf], bb1v[nf]};
            #pragma unroll
            for (int ks = 0; ks < 2; ks++){
                int kch = l4 + ks*4;
                #pragma unroll
                for (int nf = 0; nf < 8; nf++){
                    int n = nf*16 + l15;
                    s16x8 b = *(const s16x8*)(lds + 32768 + n*128 + ((kch << 4) ^ ((n & 7) << 4)));
                    acc[0][nf] = __builtin_amdgcn_mfma_f32_16x16x32_bf16(af[0][ks], b, acc[0][nf], 0, 0, 0);
                    acc[1][nf] = __builtin_amdgcn_mfma_f32_16x16x32_bf16(af[1][ks], b, acc[1][nf], 0, 0, 0);
                }
            }
            #pragma unroll
            for (int mi = 0; mi < 2; mi++)
            #pragma unroll
            for (int nf = 0; nf < 8; nf++){
                int ncol = nf*16 + l15;
                #pragma unroll
                for (int q = 0; q < 4; q++){
                    int mrow = w*32 + mi*16 + l4*4 + q;
                    float hv = fmaxf(acc[mi][nf][q], 0.f);
                    *(unsigned short*)(lds + mrow*256 + (((ncol >> 3) << 4) ^ ((mrow & 7) << 4)) + (ncol & 7)*2) = f2bf(hv);
                }
            }
        }
        __syncthreads();
        // ---- stage w2 @32768 (bc_w2T [o=64][j=128]) ----
        {
            const u32x4* src = (const u32x4*)(wb + 65536 + (long)layer*8192);
            for (int cq = t; cq < 1024; cq += 256){
                int r = cq >> 4, c16 = cq & 15;
                *(u32x4*)(lds + 32768 + r*256 + ((c16 << 4) ^ ((r & 7) << 4))) = src[cq];
            }
        }
        __syncthreads();

        // ---- G2: xnew = x_old - (h@w2 + b2); w2 from LDS; x_old from global ----
        unsigned int xnpk2[2][4][2];
        {
            unsigned short xo[2][4][4];
            #pragma unroll
            for (int mi = 0; mi < 2; mi++)
            #pragma unroll
            for (int nf = 0; nf < 4; nf++)
            #pragma unroll
            for (int q = 0; q < 4; q++){
                int mrow = w*32 + mi*16 + l4*4 + q;
                xo[mi][nf][q] = Xg[xbase + (long)mrow*64 + nf*16 + l15];
            }
            f32x4 acc[2][4];
            #pragma unroll
            for (int mi = 0; mi < 2; mi++)
            #pragma unroll
            for (int nf = 0; nf < 4; nf++)
                acc[mi][nf] = (f32x4){bb2v[nf], bb2v[nf], bb2v[nf], bb2v[nf]};
            #pragma unroll
            for (int ks = 0; ks < 4; ks++){
                int kch = l4 + ks*4;
                int r0 = w*32 + l15, r1 = w*32 + 16 + l15;
                s16x8 a0 = *(const s16x8*)(lds + r0*256 + ((kch << 4) ^ ((r0 & 7) << 4)));
                s16x8 a1 = *(const s16x8*)(lds + r1*256 + ((kch << 4) ^ ((r1 & 7) << 4)));
                #pragma unroll
                for (int nf = 0; nf < 4; nf++){
                    int n = nf*16 + l15;
                    s16x8 b = *(const s16x8*)(lds + 32768 + n*256 + ((kch << 4) ^ ((n & 7) << 4)));
                    acc[0][nf] = __builtin_amdgcn_mfma_f32_16x16x32_bf16(a0, b, acc[0][nf], 0, 0, 0);
                    acc[1][nf] = __builtin_amdgcn_mfma_f32_16x16x32_bf16(a1, b, acc[1][nf], 0, 0, 0);
                }
            }
            #pragma unroll
            for (int mi = 0; mi < 2; mi++)
            #pragma unroll
            for (int nf = 0; nf < 4; nf++){
                float xn[4];
                #pragma unroll
                for (int q = 0; q < 4; q++)
                    xn[q] = bf2f(xo[mi][nf][q]) - acc[mi][nf][q];
                xnpk2[mi][nf][0] = cvtpk(xn[0], xn[1]);
                xnpk2[mi][nf][1] = cvtpk(xn[2], xn[3]);
            }
        }
        __syncthreads();
        // ---- stage Xnew @0 (over dead H) ; stage fw1 @32768 (over dead w2) ----
        #pragma unroll
        for (int mi = 0; mi < 2; mi++)
        #pragma unroll
        for (int nf = 0; nf < 4; nf++){
            int ncol = nf*16 + l15;
            #pragma unroll
            for (int q = 0; q < 4; q++){
                int mrow = w*32 + mi*16 + l4*4 + q;
                unsigned int pk = xnpk2[mi][nf][q >> 1];
                unsigned short v = (q & 1) ? (unsigned short)(pk >> 16) : (unsigned short)(pk & 0xffffu);
                *(unsigned short*)(lds + mrow*128 + ((ncol*2) ^ ((mrow & 7) << 4))) = v;
            }
        }
        {
            const u32x4* src = (const u32x4*)(wb + 32768 + (long)layer*8192);
            for (int cq = t; cq < 1024; cq += 256){
                int r = cq >> 3, c8 = cq & 7;
                *(u32x4*)(lds + 32768 + r*128 + ((c8 << 4) ^ ((r & 7) << 4))) = src[cq];
            }
        }
        __syncthreads();
        // ---- copyout X (64B/thread contiguous) ----
        {
            int n = t >> 1, half = t & 1;
            const char* src = lds + n*128;
            unsigned short* Xdst = Xg + xbase + n*64 + half*32;
            #pragma unroll
            for (int j = 0; j < 4; j++){
                int ch = half*4 + j;
                u32x4 v = *(const u32x4*)(src + ((ch*16) ^ ((n & 7) << 4)));
                *(u32x4*)(Xdst + j*8) = v;
            }
        }
    }

    // ---- G3 (fc): h2 = relu(xs@fw1 + fb1); fw1 from LDS @32768; head from acc ----
    {
        f32x4 acc[2][8];
        #pragma unroll
        for (int mi = 0; mi < 2; mi++)
        #pragma unroll
        for (int nf = 0; nf < 8; nf++)
            acc[mi][nf] = (f32x4){fb1v[nf], fb1v[nf], fb1v[nf], fb1v[nf]};
        #pragma unroll
        for (int ks = 0; ks < 2; ks++){
            int kch = l4 + ks*4;
            #pragma unroll
            for (int nf = 0; nf < 8; nf++){
                int n = nf*16 + l15;
                s16x8 b = *(const s16x8*)(lds + 32768 + n*128 + ((kch << 4) ^ ((n & 7) << 4)));
                acc[0][nf] = __builtin_amdgcn_mfma_f32_16x16x32_bf16(af[0][ks], b, acc[0][nf], 0, 0, 0);
                acc[1][nf] = __builtin_amdgcn_mfma_f32_16x16x32_bf16(af[1][ks], b, acc[1][nf], 0, 0, 0);
            }
        }
        #pragma unroll
        for (int mi = 0; mi < 2; mi++)
        #pragma unroll
        for (int q = 0; q < 4; q++){
            float s = 0.f;
            #pragma unroll
            for (int nf = 0; nf < 8; nf++)
                s += fmaxf(acc[mi][nf][q], 0.f) * uv[nf];
            s += __shfl_xor(s, 1);
            s += __shfl_xor(s, 2);
            s += __shfl_xor(s, 4);
            s += __shfl_xor(s, 8);
            if (l15 == 0){
                int r = w*32 + mi*16 + l4*4 + q;
                long g = slab*128 + r;
                float fo = s + ddv;
                out[g] = first ? fo : (out[g] + fo);
            }
        }
    }
}

// ============ host launch ============
extern "C" void kernel_launch(void* const* d_in, const int* in_sizes, int n_in,
                              void* d_out, int out_size, void* d_ws, size_t ws_size,
                              hipStream_t stream){
    if (ws_size < (size_t)WS_NEEDED) return;
    const float* xin    = (const float*)d_in[0];
    const float* in_w   = (const float*)d_in[1];
    const float* in_b   = (const float*)d_in[2];
    const float* fwy_re = (const float*)d_in[3];
    const float* fwy_im = (const float*)d_in[4];
    const float* fwx_re = (const float*)d_in[5];
    const float* fwx_im = (const float*)d_in[6];
    const float* bc_w1  = (const float*)d_in[7];
    const float* bc_b1  = (const float*)d_in[8];
    const float* bc_w2  = (const float*)d_in[9];
    const float* bc_b2  = (const float*)d_in[10];
    const float* fc_w1  = (const float*)d_in[11];
    const float* fc_b1  = (const float*)d_in[12];
    const float* fc_w2  = (const float*)d_in[13];
    const float* fc_b2  = (const float*)d_in[14];
    const float* out_w1 = (const float*)d_in[15];
    const float* out_b1 = (const float*)d_in[16];
    const float* out_w2 = (const float*)d_in[17];
    const float* out_b2 = (const float*)d_in[18];
    float* ws  = (float*)d_ws;
    float* out = (float*)d_out;

    k_init<<<1, 256, 0, stream>>>(out_w1, out_b1, out_w2, out_b2, fc_w2, fc_b2, ws);
    k_wconv<<<384, 256, 0, stream>>>(bc_w1, fc_w1, bc_w2, ws);
    k_wmix<<<2048, 256, 0, stream>>>(fwy_re, fwy_im, fwx_re, fwx_im, ws);
    k_embed<<<32768, 256, 0, stream>>>(xin, in_w, in_b, (unsigned short*)((char*)ws + WSB_X));

    for (int l = 0; l < NL; l++){
        k_spec_x<<<1024, 256, 0, stream>>>(ws, l);
        k_spec_y_ff<<<2048, 256, 0, stream>>>(ws, out, bc_b1, bc_b2, fc_b1, l, l == 0 ? 1 : 0);
    }
}